// Round 13
// baseline (182.333 us; speedup 1.0000x reference)
//
#include <hip/hip_runtime.h>
#include <hip/hip_bf16.h>

#define BN 8
#define NN 2000
#define LL 128
#define EE 2048
#define DIN 258
#define KPAD 264
#define NROWS (BN*NN)
#define PENALTY_V 10.0f
#define CANDCAP 256
#define T0 0.092f
#define SPLITK 16
#define ECHUNK (EE/SPLITK)   // 128
#define RPB 4                // rows (waves) per block in kPB
#define NBINS 256
// kPB arena (words): [0..3999] per-wave 1000-word slots (hist 256 + cand 512),
//                    later aliased as 2-row rowbuf for output
//                    [4000..5055] x vectors (4 x 264); [5056..5567] oidx (4 x 128)
#define AWORDS 5568          // 22272 B

// ---------------- Kernel A1: partial Wc = W1@W2 over one K-slice ----------------
__global__ __launch_bounds__(256) void kA1(const float* __restrict__ W1,
                                           const float* __restrict__ b1,
                                           const float* __restrict__ W2,
                                           float* __restrict__ part) {
    __shared__ float As2[8][64];
    const int t = threadIdx.x;
    const int j = t & 127;
    const int half = t >> 7;              // 0 or 1
    const int rg = blockIdx.x >> 4;       // row group 0..32
    const int ks = blockIdx.x & 15;       // K slice 0..15
    const int k0 = rg * 8;
    const int ebase = ks * ECHUNK;
    float acc[4] = {0.f, 0.f, 0.f, 0.f};
    for (int ec = ebase; ec < ebase + ECHUNK; ec += 64) {
        #pragma unroll
        for (int q = 0; q < 2; ++q) {
            int linear = q * 256 + t;
            int r8 = linear >> 6;
            int e  = linear & 63;
            int k  = k0 + r8;
            float v;
            if (k < DIN)       v = W1[k * EE + ec + e];
            else if (k == DIN) v = b1[ec + e];
            else               v = 0.0f;
            As2[r8][e] = v;
        }
        __syncthreads();
        #pragma unroll 8
        for (int e = 0; e < 64; ++e) {
            float w = W2[(ec + e) * LL + j];
            #pragma unroll
            for (int rr = 0; rr < 4; ++rr)
                acc[rr] += As2[half * 4 + rr][e] * w;
        }
        __syncthreads();
    }
    #pragma unroll
    for (int rr = 0; rr < 4; ++rr) {
        int k = k0 + half * 4 + rr;       // < KPAD always (max 263)
        part[(size_t)ks * (KPAD * LL) + k * LL + j] = acc[rr];
    }
}

// ------------- Kernel A2: reduce partials -> WcT (transposed: [j][k]), bc -------------
__global__ __launch_bounds__(256) void kA2(const float* __restrict__ part,
                                           const float* __restrict__ b2,
                                           float* __restrict__ WcT,
                                           float* __restrict__ bc) {
    const int i = blockIdx.x * 256 + threadIdx.x;   // 0..KPAD*LL-1, i = k*LL + j
    float s = 0.f;
    #pragma unroll
    for (int q = 0; q < SPLITK; ++q) s += part[(size_t)q * (KPAD * LL) + i];
    const int k = i >> 7;
    const int j = i & 127;
    if (k == DIN)      { bc[j] = s + b2[j]; WcT[j * KPAD + k] = 0.f; }
    else if (k > DIN)  { WcT[j * KPAD + k] = 0.f; }
    else               { WcT[j * KPAD + k] = s; }
}

// ---------------- Kernel Z: zero per-row cursors ----------------
__global__ __launch_bounds__(256) void kZ(unsigned int* __restrict__ cursor) {
    int i = blockIdx.x * 256 + threadIdx.x;
    if (i < NROWS) cursor[i] = 0u;
}

// ---- Kernel PA: stream dist, compact candidates (v <= T0) to global per-row lists ----
__global__ __launch_bounds__(256) void kPA(const float* __restrict__ dist,
                                           unsigned long long* __restrict__ candg,
                                           unsigned int* __restrict__ cursor) {
    const int t = threadIdx.x;
    const int lane = t & 63;
    const int row = blockIdx.x;
    unsigned int v[8];
    unsigned int mask8 = 0u;
    int cnt_l = 0;
    if (t < 250) {
        const uint4* d4 = (const uint4*)(dist + (size_t)row * NN);
        uint4 a = d4[2 * t], b = d4[2 * t + 1];
        v[0] = a.x; v[1] = a.y; v[2] = a.z; v[3] = a.w;
        v[4] = b.x; v[5] = b.y; v[6] = b.z; v[7] = b.w;
        #pragma unroll
        for (int e = 0; e < 8; ++e)
            if (__uint_as_float(v[e]) <= T0) mask8 |= (1u << e);
        cnt_l = __builtin_popcount(mask8);
    }
    int inc = cnt_l;
    #pragma unroll
    for (int d = 1; d < 64; d <<= 1) {
        int o = __shfl_up(inc, d);
        if (lane >= d) inc += o;
    }
    const int excl = inc - cnt_l;
    unsigned int ret = 0u;
    if (lane == 63) ret = atomicAdd(&cursor[row], (unsigned int)inc);
    const unsigned int base = (unsigned int)__shfl((int)ret, 63);
    unsigned int off = base + (unsigned int)excl;
    #pragma unroll
    for (int e = 0; e < 8; ++e) {
        if ((mask8 >> e) & 1u) {
            if (off < (unsigned int)CANDCAP)
                candg[(size_t)row * CANDCAP + off] =
                    ((unsigned long long)v[e] << 32) | (unsigned int)(8 * t + e);
            ++off;
        }
    }
}

// ---- Kernel PB: bucket-rank precompacted candidates + WcT GEMV + 2-pass output ----
__global__ __launch_bounds__(256) void kPB(const float* __restrict__ dist,
                                           const float* __restrict__ theta,
                                           const float* __restrict__ f0,
                                           const float* __restrict__ f1,
                                           const unsigned long long* __restrict__ candg,
                                           const unsigned int* __restrict__ cursor,
                                           const float* __restrict__ WcT,
                                           const float* __restrict__ bc,
                                           float* __restrict__ out) {
    __shared__ __align__(16) unsigned int arena[AWORDS];   // 22272 B
    const int t = threadIdx.x;
    const int lane = t & 63;
    const int w = t >> 6;
    const int row = blockIdx.x * RPB + w;

    float* xv = (float*)&arena[4000 + w * 264];
    int* oidx = (int*)&arena[5056 + w * 128];
    unsigned int* hist = &arena[w * 1000];                                   // 256 words
    unsigned long long* cand = (unsigned long long*)&arena[w * 1000 + 256];  // 256 u64
    const unsigned int cnt = cursor[row];

    if (cnt >= (unsigned int)LL && cnt <= (unsigned int)CANDCAP) {
        // ---- common path: R8 bucket machinery on precompacted candidates ----
        // init hist (cand slots don't need init: only [0,cnt) ever read)
        {
            uint4 z4 = {0u, 0u, 0u, 0u};
            *(uint4*)&hist[lane * 4] = z4;
        }
        // load my up-to-4 keys; issue theta gathers immediately
        unsigned long long ks[4];
        float th[4];
        const unsigned long long* cg = candg + (size_t)row * CANDCAP;
        #pragma unroll
        for (int s = 0; s < 4; ++s)
            ks[s] = ((unsigned int)(lane + s * 64) < cnt) ? cg[lane + s * 64] : ~0ULL;
        #pragma unroll
        for (int s = 0; s < 4; ++s)
            if (ks[s] != ~0ULL)
                th[s] = theta[(size_t)row * NN + (unsigned int)ks[s]];
        // histogram (compile-time scale: all candidate values <= T0)
        const float scaleT = (float)(NBINS - 1) / T0;
        int bk[4];
        #pragma unroll
        for (int s = 0; s < 4; ++s) {
            if (ks[s] != ~0ULL) {
                float f = __uint_as_float((unsigned int)(ks[s] >> 32));
                int b = (int)(f * scaleT);
                bk[s] = b > NBINS - 1 ? NBINS - 1 : b;
                atomicAdd(&hist[bk[s]], 1u);
            }
        }
        // wave-synchronous exclusive scan: 4 consecutive bins per lane
        {
            uint4* h4 = (uint4*)&hist[lane * 4];
            uint4 a0 = *h4;
            unsigned int c[4] = {a0.x, a0.y, a0.z, a0.w};
            unsigned int loc[4], run = 0;
            #pragma unroll
            for (int k = 0; k < 4; ++k) { loc[k] = run; run += c[k]; }
            unsigned int inc = run;
            #pragma unroll
            for (int d = 1; d < 64; d <<= 1) {
                unsigned int o = (unsigned int)__shfl_up((int)inc, d);
                if (lane >= d) inc += o;
            }
            const unsigned int excl = inc - run;
            uint4 s0 = {excl + loc[0], excl + loc[1], excl + loc[2], excl + loc[3]};
            *h4 = s0;
        }
        // placement: slot = start(lo16) + placed(hi16)
        #pragma unroll
        for (int s = 0; s < 4; ++s) {
            if (ks[s] != ~0ULL) {
                unsigned int old = atomicAdd(&hist[bk[s]], 0x10000u);
                unsigned int slot = (old & 0xFFFFu) + (old >> 16);
                cand[slot] = ks[s];       // slot < cnt <= 256 always
            }
        }
        // within-bucket exact rank on (bits,idx); buckets are tiny (avg < 1)
        #pragma unroll
        for (int s = 0; s < 4; ++s) {
            if (ks[s] != ~0ULL) {
                unsigned int word = hist[bk[s]];
                unsigned int start = word & 0xFFFFu;
                unsigned int end = start + (word >> 16);
                unsigned int r = start;
                for (unsigned int jj = start; jj < end; ++jj) r += (cand[jj] < ks[s]);
                if (r < (unsigned int)LL) {
                    xv[r] = __uint_as_float((unsigned int)(ks[s] >> 32));
                    xv[LL + r] = th[s];
                    oidx[r] = (int)(unsigned int)ks[s];
                }
            }
        }
    } else {
        // ---- rare exact fallback: full select from dist (R10 machinery) ----
        {
            uint4 z4 = {0u, 0u, 0u, 0u};
            *(uint4*)&hist[lane * 4] = z4;
            unsigned long long f1v = ~0ULL;
            #pragma unroll
            for (int q = 0; q < CANDCAP / 64; ++q) cand[lane + q * 64] = f1v;
        }
        unsigned int v[32];
        const int nv = (lane < 52) ? 32 : 28;
        {
            const uint4* drow4 = (const uint4*)(dist + (size_t)row * NN);
            #pragma unroll
            for (int q = 0; q < 8; ++q) {
                int qi = q * 64 + lane;
                if (qi < NN / 4) {
                    uint4 a = drow4[qi];
                    v[4 * q] = a.x; v[4 * q + 1] = a.y;
                    v[4 * q + 2] = a.z; v[4 * q + 3] = a.w;
                }
            }
        }
        float T = T0;
        unsigned int qm = 0u;
        {
            unsigned int lmax = 0u;
            #pragma unroll
            for (int k = 0; k < 32; ++k) if (k < nv) lmax = max(lmax, v[k]);
            #pragma unroll
            for (int d = 1; d < 64; d <<= 1) lmax = max(lmax, (unsigned int)__shfl_xor((int)lmax, d));
            float lo = 0.0f, hi = __uint_as_float(lmax);
            if (cnt < (unsigned int)LL) lo = T; else hi = T;
            for (int it = 0; it < 32; ++it) {
                T = 0.5f * (lo + hi);
                unsigned int m = 0u;
                #pragma unroll
                for (int k = 0; k < 32; ++k)
                    if (k < nv && __uint_as_float(v[k]) <= T) m |= (1u << k);
                int c = __builtin_popcount(m);
                #pragma unroll
                for (int d = 1; d < 64; d <<= 1) c += __shfl_xor(c, d);
                qm = m;
                if (c >= LL && c <= CANDCAP) break;
                if (c < LL) lo = T; else hi = T;
            }
        }
        const float scale2 = (float)(NBINS - 1) / T;
        #pragma unroll
        for (int k = 0; k < 32; ++k) {
            if ((qm >> k) & 1u) {
                float f = __uint_as_float(v[k]);
                int b = (int)(f * scale2);
                b = b > NBINS - 1 ? NBINS - 1 : b;
                atomicAdd(&hist[b], 1u);
            }
        }
        {
            uint4* h4 = (uint4*)&hist[lane * 4];
            uint4 a0 = *h4;
            unsigned int c[4] = {a0.x, a0.y, a0.z, a0.w};
            unsigned int loc[4], run = 0;
            #pragma unroll
            for (int k = 0; k < 4; ++k) { loc[k] = run; run += c[k]; }
            unsigned int inc = run;
            #pragma unroll
            for (int d = 1; d < 64; d <<= 1) {
                unsigned int o = (unsigned int)__shfl_up((int)inc, d);
                if (lane >= d) inc += o;
            }
            const unsigned int excl = inc - run;
            uint4 s0 = {excl + loc[0], excl + loc[1], excl + loc[2], excl + loc[3]};
            *h4 = s0;
        }
        #pragma unroll
        for (int k = 0; k < 32; ++k) {
            if ((qm >> k) & 1u) {
                unsigned int bits = v[k];
                float f = __uint_as_float(bits);
                int b = (int)(f * scale2);
                b = b > NBINS - 1 ? NBINS - 1 : b;
                unsigned int old = atomicAdd(&hist[b], 0x10000u);
                unsigned int slot = (old & 0xFFFFu) + (old >> 16);
                unsigned int idx = (unsigned int)((k >> 2) * 256 + lane * 4 + (k & 3));
                if (slot < (unsigned int)CANDCAP)
                    cand[slot] = ((unsigned long long)bits << 32) | idx;
            }
        }
        {
            unsigned long long key_s[CANDCAP / 64];
            float th_s[CANDCAP / 64];
            #pragma unroll
            for (int s = 0; s < CANDCAP / 64; ++s) key_s[s] = cand[lane + s * 64];
            #pragma unroll
            for (int s = 0; s < CANDCAP / 64; ++s)
                if (key_s[s] != ~0ULL)
                    th_s[s] = theta[(size_t)row * NN + (unsigned int)key_s[s]];
            #pragma unroll
            for (int s = 0; s < CANDCAP / 64; ++s) {
                unsigned long long key = key_s[s];
                if (key != ~0ULL) {
                    unsigned int bits = (unsigned int)(key >> 32);
                    unsigned int idx  = (unsigned int)key;
                    float f = __uint_as_float(bits);
                    int b = (int)(f * scale2);
                    b = b > NBINS - 1 ? NBINS - 1 : b;
                    unsigned int word = hist[b];
                    unsigned int start = word & 0xFFFFu;
                    unsigned int end = start + (word >> 16);
                    if (end > (unsigned int)CANDCAP) end = (unsigned int)CANDCAP;
                    unsigned int r = start;
                    for (unsigned int jj = start; jj < end; ++jj) r += (cand[jj] < key);
                    if (r < (unsigned int)LL) {
                        xv[r] = f;
                        xv[LL + r] = th_s[s];
                        oidx[r] = (int)idx;
                    }
                }
            }
        }
    }

    // normalize dists in place + features (wave-local)
    {
        const float rdm = 1.0f / xv[LL - 1];
        xv[lane] *= rdm;
        xv[lane + 64] *= rdm;
        if (lane == 0) {
            xv[256] = f0[row];
            xv[257] = f1[row];
            #pragma unroll
            for (int z = DIN; z < KPAD; ++z) xv[z] = 0.0f;
        }
    }

    __syncthreads();   // barrier1: x/oidx visible block-wide; hist/cand slots dead

    // ---- GEMV: thread owns col j for rows {2rp, 2rp+1}; contiguous WcT row loads ----
    const int j = t & 127;
    const int rp = t >> 7;
    const float* x0 = (const float*)&arena[4000 + (2 * rp) * 264];
    const float* x1 = (const float*)&arena[4000 + (2 * rp + 1) * 264];
    const float* wrow = WcT + (size_t)j * KPAD;
    float acc0 = bc[j] - x0[j];
    float acc1 = bc[j] - x1[j];
    #pragma unroll 2
    for (int k = 0; k < KPAD; k += 8) {
        float4 wa0 = *(const float4*)&wrow[k];
        float4 wa1 = *(const float4*)&wrow[k + 4];
        float4 xa0 = *(const float4*)&x0[k];
        float4 xa1 = *(const float4*)&x0[k + 4];
        float4 xb0 = *(const float4*)&x1[k];
        float4 xb1 = *(const float4*)&x1[k + 4];
        acc0 += xa0.x * wa0.x; acc1 += xb0.x * wa0.x;
        acc0 += xa0.y * wa0.y; acc1 += xb0.y * wa0.y;
        acc0 += xa0.z * wa0.z; acc1 += xb0.z * wa0.z;
        acc0 += xa0.w * wa0.w; acc1 += xb0.w * wa0.w;
        acc0 += xa1.x * wa1.x; acc1 += xb1.x * wa1.x;
        acc0 += xa1.y * wa1.y; acc1 += xb1.y * wa1.y;
        acc0 += xa1.z * wa1.z; acc1 += xb1.z * wa1.z;
        acc0 += xa1.w * wa1.w; acc1 += xb1.w * wa1.w;
    }
    const int oi0 = ((const int*)&arena[5056 + (2 * rp) * 128])[j];
    const int oi1 = ((const int*)&arena[5056 + (2 * rp + 1) * 128])[j];

    // ---- output: 2 passes; each builds 2 FULL rows in rowbuf and streams once ----
    float* rowbuf = (float*)arena;               // 4000 words: 2 full rows
    const float4 pen4 = {PENALTY_V, PENALTY_V, PENALTY_V, PENALTY_V};
    #pragma unroll
    for (int p = 0; p < 2; ++p) {
        __syncthreads();
        for (int i = t; i < 1000; i += 256) ((float4*)rowbuf)[i] = pen4;
        __syncthreads();
        if (rp == p) {
            rowbuf[oi0] = acc0;
            rowbuf[NN + oi1] = acc1;
        }
        __syncthreads();
        float4* o4 = (float4*)(out + ((size_t)blockIdx.x * RPB + 2 * p) * NN);
        for (int i = t; i < 1000; i += 256) o4[i] = ((const float4*)rowbuf)[i];
    }
}

extern "C" void kernel_launch(void* const* d_in, const int* in_sizes, int n_in,
                              void* d_out, int out_size, void* d_ws, size_t ws_size,
                              hipStream_t stream) {
    const float* theta = (const float*)d_in[0];
    const float* dist  = (const float*)d_in[1];
    const float* f0    = (const float*)d_in[2];
    const float* f1    = (const float*)d_in[3];
    const float* W1    = (const float*)d_in[4];
    const float* b1    = (const float*)d_in[5];
    const float* W2    = (const float*)d_in[6];
    const float* b2    = (const float*)d_in[7];
    float* out = (float*)d_out;

    char* ws = (char*)d_ws;
    float* WcT  = (float*)ws;                    // 135168 B (transposed [j][k])
    float* bc   = (float*)(ws + 135168);         // 512 B
    // part (2.16 MB) is consumed by kA2 BEFORE kPA writes candg -> safe alias.
    float* part = (float*)(ws + 135680);
    unsigned long long* candg = (unsigned long long*)(ws + 135680);      // 32768000 B
    unsigned int* cursor = (unsigned int*)(ws + 135680 + 32768000);      // 64000 B

    kA1<<<33 * SPLITK, 256, 0, stream>>>(W1, b1, W2, part);
    kA2<<<(KPAD * LL) / 256, 256, 0, stream>>>(part, b2, WcT, bc);
    kZ<<<(NROWS + 255) / 256, 256, 0, stream>>>(cursor);
    kPA<<<NROWS, 256, 0, stream>>>(dist, candg, cursor);
    kPB<<<NROWS / RPB, 256, 0, stream>>>(dist, theta, f0, f1, candg, cursor, WcT, bc, out);
}

// Round 14
// 119.417 us; speedup vs baseline: 1.5269x; 1.5269x over previous
//
#include <hip/hip_runtime.h>
#include <hip/hip_bf16.h>

#define BN 8
#define NN 2000
#define LL 128
#define EE 2048
#define DIN 258
#define KPAD 264
#define NROWS (BN*NN)
#define PENALTY_V 10.0f
#define NBINS 256
#define CANDCAP 256
#define T0 0.092f
#define SPLITK 16
#define ECHUNK (EE/SPLITK)   // 128
#define RPB 4                // rows (waves) per block
// Arena (words): [0..3071] select scratch, 768/wave (hist 256 + cand 512)
//                [3072..4127] x vectors (4 x 264)
//                [4128..4639] oidx (4 x 128)
#define AWORDS 4640          // 18560 B per block -> 8 blocks/CU LDS cap

// ---------------- Kernel A1: partial Wc = W1@W2 over one K-slice ----------------
__global__ __launch_bounds__(256) void kA1(const float* __restrict__ W1,
                                           const float* __restrict__ b1,
                                           const float* __restrict__ W2,
                                           float* __restrict__ part) {
    __shared__ float As2[8][64];
    const int t = threadIdx.x;
    const int j = t & 127;
    const int half = t >> 7;              // 0 or 1
    const int rg = blockIdx.x >> 4;       // row group 0..32
    const int ks = blockIdx.x & 15;       // K slice 0..15
    const int k0 = rg * 8;
    const int ebase = ks * ECHUNK;
    float acc[4] = {0.f, 0.f, 0.f, 0.f};
    for (int ec = ebase; ec < ebase + ECHUNK; ec += 64) {
        #pragma unroll
        for (int q = 0; q < 2; ++q) {
            int linear = q * 256 + t;
            int r8 = linear >> 6;
            int e  = linear & 63;
            int k  = k0 + r8;
            float v;
            if (k < DIN)       v = W1[k * EE + ec + e];
            else if (k == DIN) v = b1[ec + e];
            else               v = 0.0f;
            As2[r8][e] = v;
        }
        __syncthreads();
        #pragma unroll 8
        for (int e = 0; e < 64; ++e) {
            float w = W2[(ec + e) * LL + j];
            #pragma unroll
            for (int rr = 0; rr < 4; ++rr)
                acc[rr] += As2[half * 4 + rr][e] * w;
        }
        __syncthreads();
    }
    #pragma unroll
    for (int rr = 0; rr < 4; ++rr) {
        int k = k0 + half * 4 + rr;       // < KPAD always (max 263)
        part[(size_t)ks * (KPAD * LL) + k * LL + j] = acc[rr];
    }
}

// ---------------- Kernel A2: reduce partials -> Wc, bc ----------------
__global__ __launch_bounds__(256) void kA2(const float* __restrict__ part,
                                           const float* __restrict__ b2,
                                           float* __restrict__ Wc,
                                           float* __restrict__ bc) {
    const int i = blockIdx.x * 256 + threadIdx.x;   // 0..KPAD*LL-1
    float s = 0.f;
    #pragma unroll
    for (int q = 0; q < SPLITK; ++q) s += part[(size_t)q * (KPAD * LL) + i];
    const int k = i >> 7;
    const int j = i & 127;
    if (k == DIN)      { bc[j] = s + b2[j]; Wc[i] = 0.f; }
    else if (k > DIN)  { Wc[i] = 0.f; }
    else               { Wc[i] = s; }
}

// ---- Kernel F: fused select + deep-ILP GEMV + direct-to-global PENALTY/scatter out ----
__global__ __launch_bounds__(256) void kF(const float* __restrict__ dist,
                                          const float* __restrict__ theta,
                                          const float* __restrict__ f0,
                                          const float* __restrict__ f1,
                                          const float* __restrict__ Wc,
                                          const float* __restrict__ bc,
                                          float* __restrict__ out) {
    __shared__ __align__(16) unsigned int arena[AWORDS];   // 18560 B
    const int t = threadIdx.x;
    const int lane = t & 63;
    const int w = t >> 6;
    const int row = blockIdx.x * RPB + w;

    unsigned int* hist = &arena[w * 768];                        // 256 words (scratch)
    unsigned long long* cand = (unsigned long long*)&arena[w * 768 + 256]; // 256 u64
    float* xv = (float*)&arena[3072 + w * 264];                  // 264 floats
    int* oidx = (int*)&arena[4128 + w * 128];                    // 128 ints

    // ---- select phase: wave-local, no barriers (identical logic to R8/R11) ----
    {
        uint4 z4 = {0u, 0u, 0u, 0u};
        *(uint4*)&hist[lane * 4] = z4;
        unsigned long long f1v = ~0ULL;
        #pragma unroll
        for (int q = 0; q < CANDCAP / 64; ++q) cand[lane + q * 64] = f1v;
    }

    unsigned int v[32];
    const int nv = (lane < 52) ? 32 : 28;    // 500 uint4 = 7*64 + 52
    {
        const uint4* drow4 = (const uint4*)(dist + (size_t)row * NN);
        #pragma unroll
        for (int q = 0; q < 8; ++q) {
            int qi = q * 64 + lane;
            if (qi < NN / 4) {
                uint4 a = drow4[qi];
                v[4 * q]     = a.x;
                v[4 * q + 1] = a.y;
                v[4 * q + 2] = a.z;
                v[4 * q + 3] = a.w;
            }
        }
    }

    float T = T0;
    unsigned int qm = 0u;
    #pragma unroll
    for (int k = 0; k < 32; ++k)
        if (k < nv && __uint_as_float(v[k]) <= T) qm |= (1u << k);
    int cnt = __builtin_popcount(qm);
    #pragma unroll
    for (int d = 1; d < 64; d <<= 1) cnt += __shfl_xor(cnt, d);

    if (cnt < LL || cnt > CANDCAP) {
        // cold fallback: exact bisection to land count in [LL, CANDCAP]
        unsigned int lmax = 0u;
        #pragma unroll
        for (int k = 0; k < 32; ++k) if (k < nv) lmax = max(lmax, v[k]);
        #pragma unroll
        for (int d = 1; d < 64; d <<= 1) lmax = max(lmax, (unsigned int)__shfl_xor((int)lmax, d));
        float lo = 0.0f, hi = __uint_as_float(lmax);
        if (cnt < LL) lo = T; else hi = T;
        for (int it = 0; it < 32; ++it) {
            T = 0.5f * (lo + hi);
            unsigned int m = 0u;
            #pragma unroll
            for (int k = 0; k < 32; ++k)
                if (k < nv && __uint_as_float(v[k]) <= T) m |= (1u << k);
            int c = __builtin_popcount(m);
            #pragma unroll
            for (int d = 1; d < 64; d <<= 1) c += __shfl_xor(c, d);
            qm = m;
            if (c >= LL && c <= CANDCAP) break;
            if (c < LL) lo = T; else hi = T;
        }
    }
    const float scale2 = (float)(NBINS - 1) / T;

    // histogram of candidates
    #pragma unroll
    for (int k = 0; k < 32; ++k) {
        if ((qm >> k) & 1u) {
            float f = __uint_as_float(v[k]);
            int b = (int)(f * scale2);
            b = b > NBINS - 1 ? NBINS - 1 : b;
            atomicAdd(&hist[b], 1u);
        }
    }

    // wave-synchronous exclusive scan: 4 consecutive bins per lane
    {
        uint4* h4 = (uint4*)&hist[lane * 4];
        uint4 a0 = *h4;
        unsigned int c[4] = {a0.x, a0.y, a0.z, a0.w};
        unsigned int loc[4], run = 0;
        #pragma unroll
        for (int k = 0; k < 4; ++k) { loc[k] = run; run += c[k]; }
        unsigned int inc = run;
        #pragma unroll
        for (int d = 1; d < 64; d <<= 1) {
            unsigned int o = (unsigned int)__shfl_up((int)inc, d);
            if (lane >= d) inc += o;
        }
        const unsigned int excl = inc - run;
        uint4 s0 = {excl + loc[0], excl + loc[1], excl + loc[2], excl + loc[3]};
        *h4 = s0;
    }

    // placement: slot = start + arrival order (hist low16=start, high16=count)
    #pragma unroll
    for (int k = 0; k < 32; ++k) {
        if ((qm >> k) & 1u) {
            unsigned int bits = v[k];
            float f = __uint_as_float(bits);
            int b = (int)(f * scale2);
            b = b > NBINS - 1 ? NBINS - 1 : b;
            unsigned int old = atomicAdd(&hist[b], 0x10000u);
            unsigned int slot = (old & 0xFFFFu) + (old >> 16);
            unsigned int idx = (unsigned int)((k >> 2) * 256 + lane * 4 + (k & 3));
            if (slot < (unsigned int)CANDCAP)
                cand[slot] = ((unsigned long long)bits << 32) | idx;
        }
    }

    // rank phase: theta gathers issued early; write x (unnormalized) + oidx
    {
        unsigned long long key_s[CANDCAP / 64];
        float th_s[CANDCAP / 64];
        #pragma unroll
        for (int s = 0; s < CANDCAP / 64; ++s) key_s[s] = cand[lane + s * 64];
        #pragma unroll
        for (int s = 0; s < CANDCAP / 64; ++s)
            if (key_s[s] != ~0ULL)
                th_s[s] = theta[(size_t)row * NN + (unsigned int)key_s[s]];
        #pragma unroll
        for (int s = 0; s < CANDCAP / 64; ++s) {
            unsigned long long key = key_s[s];
            if (key != ~0ULL) {
                unsigned int bits = (unsigned int)(key >> 32);
                unsigned int idx  = (unsigned int)key;
                float f = __uint_as_float(bits);
                int b = (int)(f * scale2);
                b = b > NBINS - 1 ? NBINS - 1 : b;
                unsigned int word = hist[b];
                unsigned int start = word & 0xFFFFu;
                unsigned int end = start + (word >> 16);
                if (end > (unsigned int)CANDCAP) end = (unsigned int)CANDCAP;
                unsigned int r = start;
                for (unsigned int jj = start; jj < end; ++jj) r += (cand[jj] < key);
                if (r < (unsigned int)LL) {
                    xv[r] = f;
                    xv[LL + r] = th_s[s];
                    oidx[r] = (int)idx;
                }
            }
        }
    }

    // normalize dists in place + features (wave-local; program order guarantees)
    {
        const float rdm = 1.0f / xv[LL - 1];
        xv[lane] *= rdm;
        xv[lane + 64] *= rdm;
        if (lane == 0) {
            xv[256] = f0[row];
            xv[257] = f1[row];
            #pragma unroll
            for (int z = DIN; z < KPAD; ++z) xv[z] = 0.0f;
        }
    }

    __syncthreads();   // barrier1: x/oidx visible block-wide

    // ---- GEMV: thread owns col j for rows {2rp, 2rp+1}; deep-ILP k-loop ----
    const int j = t & 127;
    const int rp = t >> 7;
    const float* x0 = (const float*)&arena[3072 + (2 * rp) * 264];
    const float* x1 = (const float*)&arena[3072 + (2 * rp + 1) * 264];
    float acc0 = bc[j] - x0[j];
    float acc1 = bc[j] - x1[j];
    #pragma unroll 2
    for (int k = 0; k < KPAD; k += 8) {
        float w0 = Wc[(k + 0) * LL + j];
        float w1 = Wc[(k + 1) * LL + j];
        float w2 = Wc[(k + 2) * LL + j];
        float w3 = Wc[(k + 3) * LL + j];
        float w4 = Wc[(k + 4) * LL + j];
        float w5 = Wc[(k + 5) * LL + j];
        float w6 = Wc[(k + 6) * LL + j];
        float w7 = Wc[(k + 7) * LL + j];
        float4 xa0 = *(const float4*)&x0[k];
        float4 xa1 = *(const float4*)&x0[k + 4];
        float4 xb0 = *(const float4*)&x1[k];
        float4 xb1 = *(const float4*)&x1[k + 4];
        acc0 += xa0.x * w0; acc1 += xb0.x * w0;
        acc0 += xa0.y * w1; acc1 += xb0.y * w1;
        acc0 += xa0.z * w2; acc1 += xb0.z * w2;
        acc0 += xa0.w * w3; acc1 += xb0.w * w3;
        acc0 += xa1.x * w4; acc1 += xb1.x * w4;
        acc0 += xa1.y * w5; acc1 += xb1.y * w5;
        acc0 += xa1.z * w6; acc1 += xb1.z * w6;
        acc0 += xa1.w * w7; acc1 += xb1.w * w7;
    }
    const int oi0 = ((const int*)&arena[4128 + (2 * rp) * 128])[j];
    const int oi1 = ((const int*)&arena[4128 + (2 * rp + 1) * 128])[j];

    // ---- output: PENALTY-fill 4 rows directly in global (full-line float4 stores),
    //      block fence, then scatter register accs (4B stores merge in L2) ----
    {
        const float4 pen4 = {PENALTY_V, PENALTY_V, PENALTY_V, PENALTY_V};
        float4* ob = (float4*)(out + (size_t)blockIdx.x * RPB * NN);   // 2000 float4
        #pragma unroll
        for (int q = 0; q < 8; ++q) {
            int i = q * 256 + t;
            if (i < RPB * (NN / 4)) ob[i] = pen4;
        }
        __syncthreads();   // fills complete (vmcnt drained) before scatter
        out[((size_t)blockIdx.x * RPB + 2 * rp) * NN + oi0] = acc0;
        out[((size_t)blockIdx.x * RPB + 2 * rp + 1) * NN + oi1] = acc1;
    }
}

extern "C" void kernel_launch(void* const* d_in, const int* in_sizes, int n_in,
                              void* d_out, int out_size, void* d_ws, size_t ws_size,
                              hipStream_t stream) {
    const float* theta = (const float*)d_in[0];
    const float* dist  = (const float*)d_in[1];
    const float* f0    = (const float*)d_in[2];
    const float* f1    = (const float*)d_in[3];
    const float* W1    = (const float*)d_in[4];
    const float* b1    = (const float*)d_in[5];
    const float* W2    = (const float*)d_in[6];
    const float* b2    = (const float*)d_in[7];
    float* out = (float*)d_out;

    char* ws = (char*)d_ws;
    float* Wc   = (float*)ws;                    // KPAD*128*4 = 135168
    float* bc   = (float*)(ws + 135168);         // 512
    float* part = (float*)(ws + 135680);         // SPLITK*KPAD*128*4 = 2162688

    kA1<<<33 * SPLITK, 256, 0, stream>>>(W1, b1, W2, part);
    kA2<<<(KPAD * LL) / 256, 256, 0, stream>>>(part, b2, Wc, bc);
    kF<<<NROWS / RPB, 256, 0, stream>>>(dist, theta, f0, f1, Wc, bc, out);
}